// Round 1
// baseline (1523.760 us; speedup 1.0000x reference)
//
#include <hip/hip_runtime.h>
#include <hip/hip_bf16.h>

#define N_NODES 50000
#define N_EDGES 800000
#define NFEAT   512
#define NHID    64
#define NHEADS  8
#define NCLASS  40
#define HD      (NHEADS*NHID)   // 512
#define ALPHA   0.2f
#define EPS_F   1e-16f
#define NCHUNK  ((N_NODES + 255)/256)   // 196

// ---------------------------------------------------------------------------
// Repack W_heads [H][512][64] -> Wcat [512][512] row-major, col j = hd*64+d
__global__ void repackW(const float* __restrict__ Wh, float* __restrict__ Wr) {
    int idx = blockIdx.x*256 + threadIdx.x;      // < 512*512
    if (idx >= 512*512) return;
    int k = idx >> 9;        // feature (row)
    int j = idx & 511;       // out col
    int hd = j >> 6, d = j & 63;
    Wr[idx] = Wh[(size_t)hd*NFEAT*NHID + (size_t)k*NHID + d];
}

// ---------------------------------------------------------------------------
// fp32 GEMM: C[M,512] = A[M,512] @ B[512,512]; 128x128 tile, BK=8, 8x8/thread
__global__ __launch_bounds__(256) void sgemm1(const float* __restrict__ A,
                                              const float* __restrict__ B,
                                              float* __restrict__ C, int M) {
    const int K = 512, N = 512;
    __shared__ float As[8][128];
    __shared__ float Bs[8][128];
    int tid  = threadIdx.x;
    int row0 = blockIdx.y * 128, col0 = blockIdx.x * 128;
    int tr = (tid >> 4) << 3;    // 0..120 step 8
    int tc = (tid & 15) << 3;

    float acc[8][8];
#pragma unroll
    for (int i = 0; i < 8; i++)
#pragma unroll
        for (int j = 0; j < 8; j++) acc[i][j] = 0.f;

    int ar = tid >> 1, ak = (tid & 1) << 2;      // A: 128 rows x 8k
    int bk = tid >> 5, bc = (tid & 31) << 2;     // B: 8k x 128 cols

    for (int k0 = 0; k0 < K; k0 += 8) {
        float4 av = make_float4(0,0,0,0);
        int arow = row0 + ar;
        if (arow < M) av = *(const float4*)(A + (size_t)arow*K + k0 + ak);
        As[ak+0][ar] = av.x; As[ak+1][ar] = av.y;
        As[ak+2][ar] = av.z; As[ak+3][ar] = av.w;
        float4 bv = *(const float4*)(B + (size_t)(k0+bk)*N + col0 + bc);
        *(float4*)(&Bs[bk][bc]) = bv;
        __syncthreads();
#pragma unroll
        for (int kk = 0; kk < 8; kk++) {
            float a[8], b[8];
#pragma unroll
            for (int i = 0; i < 8; i++) a[i] = As[kk][tr+i];
#pragma unroll
            for (int j = 0; j < 8; j++) b[j] = Bs[kk][tc+j];
#pragma unroll
            for (int i = 0; i < 8; i++)
#pragma unroll
                for (int j = 0; j < 8; j++)
                    acc[i][j] = fmaf(a[i], b[j], acc[i][j]);
        }
        __syncthreads();
    }
#pragma unroll
    for (int i = 0; i < 8; i++) {
        int r = row0 + tr + i;
        if (r < M) {
#pragma unroll
            for (int j = 0; j < 8; j += 4)
                *(float4*)(C + (size_t)r*N + col0 + tc + j) =
                    make_float4(acc[i][j], acc[i][j+1], acc[i][j+2], acc[i][j+3]);
        }
    }
}

// ---------------------------------------------------------------------------
// Per-(node,head) attention dots: src = h.a[:64], dst = h.a[64:]
__global__ void dots1(const float* __restrict__ H1, const float* __restrict__ a_heads,
                      float* __restrict__ srcdot, float* __restrict__ dstdot) {
    int t = blockIdx.x*256 + threadIdx.x;
    if (t >= N_NODES*NHEADS) return;
    int i = t >> 3, hd = t & 7;
    const float* hrow = H1 + (size_t)i*HD + hd*NHID;
    const float* as = a_heads + hd*2*NHID;
    const float* ad = as + NHID;
    float s0 = 0.f, s1 = 0.f;
#pragma unroll
    for (int d = 0; d < NHID; d += 4) {
        float4 h = *(const float4*)(hrow + d);
        float4 u = *(const float4*)(as + d);
        float4 v = *(const float4*)(ad + d);
        s0 += h.x*u.x + h.y*u.y + h.z*u.z + h.w*u.w;
        s1 += h.x*v.x + h.y*v.y + h.z*v.z + h.w*v.w;
    }
    srcdot[t] = s0; dstdot[t] = s1;
}

// Per-edge weights (all heads): w = exp(-leakyrelu(src[row]+dst[col]))
__global__ void edge_w1(const int* __restrict__ row, const int* __restrict__ col,
                        const float* __restrict__ srcdot, const float* __restrict__ dstdot,
                        float* __restrict__ Wedge) {
    int e = blockIdx.x*256 + threadIdx.x;
    if (e >= N_EDGES) return;
    int r = row[e], c = col[e];
#pragma unroll
    for (int hd = 0; hd < NHEADS; hd++) {
        float s = srcdot[r*NHEADS+hd] + dstdot[c*NHEADS+hd];
        float lr = s > 0.f ? s : ALPHA*s;
        Wedge[(size_t)e*NHEADS + hd] = __expf(-lr);
    }
}

// ---------------------------------------------------------------------------
// CSR build
__global__ void zero_deg(int* __restrict__ deg) {
    int i = blockIdx.x*256 + threadIdx.x;
    if (i < N_NODES) deg[i] = 0;
}
__global__ void histk(const int* __restrict__ row, int* __restrict__ deg) {
    int e = blockIdx.x*256 + threadIdx.x;
    if (e < N_EDGES) atomicAdd(&deg[row[e]], 1);
}
__global__ void scanA(const int* __restrict__ deg, int* __restrict__ row_ptr,
                      int* __restrict__ chunk_tot) {
    __shared__ int s[256];
    int t = threadIdx.x;
    int idx = blockIdx.x*256 + t;
    int v = (idx < N_NODES) ? deg[idx] : 0;
    s[t] = v;
    __syncthreads();
#pragma unroll
    for (int off = 1; off < 256; off <<= 1) {
        int x = (t >= off) ? s[t-off] : 0;
        __syncthreads();
        s[t] += x;
        __syncthreads();
    }
    if (idx < N_NODES) row_ptr[idx] = s[t] - v;
    if (t == 255) chunk_tot[blockIdx.x] = s[t];
}
__global__ void scanB(const int* __restrict__ chunk_tot, int* __restrict__ chunk_off,
                      int* __restrict__ row_ptr) {
    __shared__ int s[256];
    int t = threadIdx.x;
    int v = (t < NCHUNK) ? chunk_tot[t] : 0;
    s[t] = v;
    __syncthreads();
#pragma unroll
    for (int off = 1; off < 256; off <<= 1) {
        int x = (t >= off) ? s[t-off] : 0;
        __syncthreads();
        s[t] += x;
        __syncthreads();
    }
    if (t < NCHUNK) chunk_off[t] = s[t] - v;
    if (t == 255) row_ptr[N_NODES] = s[t];   // == N_EDGES
}
__global__ void scanC(const int* __restrict__ chunk_off, int* __restrict__ row_ptr,
                      int* __restrict__ cursor) {
    int idx = blockIdx.x*256 + threadIdx.x;
    if (idx < N_NODES) {
        int rp = row_ptr[idx] + chunk_off[idx >> 8];
        row_ptr[idx] = rp;
        cursor[idx] = rp;
    }
}
__global__ void fillk(const int* __restrict__ row, const int* __restrict__ col,
                      int* __restrict__ cursor, int* __restrict__ csr_eid,
                      int* __restrict__ csr_col) {
    int e = blockIdx.x*256 + threadIdx.x;
    if (e >= N_EDGES) return;
    int r = row[e];
    int pos = atomicAdd(&cursor[r], 1);
    csr_eid[pos] = e;
    csr_col[pos] = col[e];
}

// ---------------------------------------------------------------------------
// Layer-1 aggregation + ELU. One wave per (node, head); lane = feature d.
__global__ __launch_bounds__(256) void agg1(const float* __restrict__ H1,
                                            const float* __restrict__ Wedge,
                                            const int* __restrict__ row_ptr,
                                            const int* __restrict__ csr_eid,
                                            const int* __restrict__ csr_col,
                                            float* __restrict__ hcat) {
    int wave = (blockIdx.x*256 + threadIdx.x) >> 6;
    int lane = threadIdx.x & 63;
    if (wave >= N_NODES*NHEADS) return;
    int i = wave >> 3, hd = wave & 7;
    int start = row_ptr[i], end = row_ptr[i+1];
    float acc = 0.f, den = 0.f;
    for (int k = start; k < end; ++k) {
        int e = csr_eid[k];
        int c = csr_col[k];
        float w = Wedge[(size_t)e*NHEADS + hd];
        den += w;
        acc = fmaf(w, H1[(size_t)c*HD + hd*NHID + lane], acc);
    }
    float o = acc / (den + EPS_F);
    o = o > 0.f ? o : (__expf(o) - 1.f);       // ELU
    hcat[(size_t)i*HD + hd*NHID + lane] = o;
}

// ---------------------------------------------------------------------------
// Layer 2: H2[N,40] = hcat[N,512] @ W_out[512,40], thread per output
__global__ void gemm2(const float* __restrict__ hcat, const float* __restrict__ Wout,
                      float* __restrict__ H2) {
    int t = blockIdx.x*256 + threadIdx.x;
    if (t >= N_NODES*NCLASS) return;
    int i = t / NCLASS, c = t - i*NCLASS;
    const float* hr = hcat + (size_t)i*HD;
    float acc = 0.f;
#pragma unroll 8
    for (int k = 0; k < HD; k++) acc = fmaf(hr[k], Wout[k*NCLASS + c], acc);
    H2[t] = acc;
}

__global__ void dots2(const float* __restrict__ H2, const float* __restrict__ a_out,
                      float* __restrict__ src2, float* __restrict__ dst2) {
    int i = blockIdx.x*256 + threadIdx.x;
    if (i >= N_NODES) return;
    float s0 = 0.f, s1 = 0.f;
#pragma unroll
    for (int c = 0; c < NCLASS; c++) {
        float h = H2[(size_t)i*NCLASS + c];
        s0 += h * a_out[c];
        s1 += h * a_out[NCLASS + c];
    }
    src2[i] = s0; dst2[i] = s1;
}

__global__ void edge_w2(const int* __restrict__ row, const int* __restrict__ col,
                        const float* __restrict__ src2, const float* __restrict__ dst2,
                        float* __restrict__ w2) {
    int e = blockIdx.x*256 + threadIdx.x;
    if (e >= N_EDGES) return;
    float s = src2[row[e]] + dst2[col[e]];
    float lr = s > 0.f ? s : ALPHA*s;
    w2[e] = __expf(-lr);
}

// Final aggregation (no ELU). One wave per node; lanes 0..39 = class.
__global__ __launch_bounds__(256) void agg2(const float* __restrict__ H2,
                                            const float* __restrict__ w2,
                                            const int* __restrict__ row_ptr,
                                            const int* __restrict__ csr_eid,
                                            const int* __restrict__ csr_col,
                                            float* __restrict__ out) {
    int wave = (blockIdx.x*256 + threadIdx.x) >> 6;
    int lane = threadIdx.x & 63;
    if (wave >= N_NODES) return;
    int start = row_ptr[wave], end = row_ptr[wave+1];
    int l = lane < NCLASS ? lane : 0;          // clamp to stay in-bounds
    float acc = 0.f, den = 0.f;
    for (int k = start; k < end; ++k) {
        int e = csr_eid[k];
        int c = csr_col[k];
        float w = w2[e];
        den += w;
        acc = fmaf(w, H2[(size_t)c*NCLASS + l], acc);
    }
    if (lane < NCLASS)
        out[(size_t)wave*NCLASS + lane] = acc / (den + EPS_F);
}

// ---------------------------------------------------------------------------
extern "C" void kernel_launch(void* const* d_in, const int* in_sizes, int n_in,
                              void* d_out, int out_size, void* d_ws, size_t ws_size,
                              hipStream_t stream) {
    const float* x       = (const float*)d_in[0];
    const float* W_heads = (const float*)d_in[1];
    const float* a_heads = (const float*)d_in[2];
    const float* W_out   = (const float*)d_in[3];
    const float* a_out   = (const float*)d_in[4];
    const int*   ei      = (const int*)d_in[5];
    const int*   row     = ei;
    const int*   col     = ei + N_EDGES;
    float* out = (float*)d_out;

    // workspace layout (256B aligned)
    char* ws = (char*)d_ws;
    size_t off = 0;
    auto alloc = [&](size_t bytes) {
        char* p = ws + off;
        off = (off + bytes + 255) & ~(size_t)255;
        return p;
    };
    float* Wr      = (float*)alloc((size_t)512*512*4);
    float* H1      = (float*)alloc((size_t)N_NODES*HD*4);
    float* hcat    = (float*)alloc((size_t)N_NODES*HD*4);
    float* srcdot  = (float*)alloc((size_t)N_NODES*NHEADS*4);
    float* dstdot  = (float*)alloc((size_t)N_NODES*NHEADS*4);
    float* Wedge   = (float*)alloc((size_t)N_EDGES*NHEADS*4);
    int*   deg     = (int*)alloc((size_t)N_NODES*4);
    int*   row_ptr = (int*)alloc((size_t)(N_NODES+1)*4);
    int*   cursor  = (int*)alloc((size_t)N_NODES*4);
    int*   ctot    = (int*)alloc(256*4);
    int*   coff    = (int*)alloc(256*4);
    int*   csr_eid = (int*)alloc((size_t)N_EDGES*4);
    int*   csr_col = (int*)alloc((size_t)N_EDGES*4);
    float* H2      = (float*)alloc((size_t)N_NODES*NCLASS*4);
    float* src2    = (float*)alloc((size_t)N_NODES*4);
    float* dst2    = (float*)alloc((size_t)N_NODES*4);
    float* w2      = (float*)alloc((size_t)N_EDGES*4);
    (void)ws_size;

    const int EB = (N_EDGES + 255)/256;     // 3125
    const int NB = (N_NODES + 255)/256;     // 196

    // Layer 1
    repackW<<<(512*512+255)/256, 256, 0, stream>>>(W_heads, Wr);
    {
        dim3 grid(512/128, (N_NODES + 127)/128);
        sgemm1<<<grid, 256, 0, stream>>>(x, Wr, H1, N_NODES);
    }
    dots1<<<(N_NODES*NHEADS + 255)/256, 256, 0, stream>>>(H1, a_heads, srcdot, dstdot);
    edge_w1<<<EB, 256, 0, stream>>>(row, col, srcdot, dstdot, Wedge);

    // CSR (shared by both layers)
    zero_deg<<<NB, 256, 0, stream>>>(deg);
    histk<<<EB, 256, 0, stream>>>(row, deg);
    scanA<<<NCHUNK, 256, 0, stream>>>(deg, row_ptr, ctot);
    scanB<<<1, 256, 0, stream>>>(ctot, coff, row_ptr);
    scanC<<<NCHUNK, 256, 0, stream>>>(coff, row_ptr, cursor);
    fillk<<<EB, 256, 0, stream>>>(row, col, cursor, csr_eid, csr_col);

    agg1<<<(N_NODES*NHEADS*64 + 255)/256, 256, 0, stream>>>(H1, Wedge, row_ptr,
                                                            csr_eid, csr_col, hcat);

    // Layer 2
    gemm2<<<(N_NODES*NCLASS + 255)/256, 256, 0, stream>>>(hcat, W_out, H2);
    dots2<<<NB, 256, 0, stream>>>(H2, a_out, src2, dst2);
    edge_w2<<<EB, 256, 0, stream>>>(row, col, src2, dst2, w2);
    agg2<<<(N_NODES*64 + 255)/256, 256, 0, stream>>>(H2, w2, row_ptr,
                                                     csr_eid, csr_col, out);
}

// Round 2
// 856.587 us; speedup vs baseline: 1.7789x; 1.7789x over previous
//
#include <hip/hip_runtime.h>
#include <hip/hip_bf16.h>

#define N_NODES 50000
#define N_EDGES 800000
#define NFEAT   512
#define NHID    64
#define NHEADS  8
#define NCLASS  40
#define HD      (NHEADS*NHID)   // 512
#define ALPHA   0.2f
#define EPS_F   1e-16f
#define NCHUNK  ((N_NODES + 255)/256)   // 196

typedef __attribute__((ext_vector_type(8))) short short8;
typedef __attribute__((ext_vector_type(4))) float floatx4;

__device__ __forceinline__ float bf2f(unsigned short u) {
    union { unsigned int i; float f; } v; v.i = ((unsigned int)u) << 16; return v.f;
}
__device__ __forceinline__ unsigned short f2bf(float f) {
    union { __hip_bfloat16 h; unsigned short u; } cv;
    cv.h = __float2bfloat16(f);
    return cv.u;
}

// ---------------------------------------------------------------------------
// Cast x [N,512] fp32 -> bf16 bits
__global__ void castX(const float* __restrict__ x, unsigned short* __restrict__ xb) {
    int idx = blockIdx.x*256 + threadIdx.x;      // one per 4 elements
    if (idx >= N_NODES*512/4) return;
    float4 v = ((const float4*)x)[idx];
    ushort4 o;
    o.x = f2bf(v.x); o.y = f2bf(v.y); o.z = f2bf(v.z); o.w = f2bf(v.w);
    ((ushort4*)xb)[idx] = o;
}

// Repack W_heads [H][512][64] -> Wrb[n][k] bf16 (B^T layout: n=hd*64+d, k=feat)
__global__ void repackWb(const float* __restrict__ Wh, unsigned short* __restrict__ Wrb) {
    int idx = blockIdx.x*256 + threadIdx.x;      // n*512 + k
    if (idx >= 512*512) return;
    int n = idx >> 9, k = idx & 511;
    int hd = n >> 6, d = n & 63;
    Wrb[idx] = f2bf(Wh[(size_t)hd*NFEAT*NHID + (size_t)k*NHID + d]);
}

// ---------------------------------------------------------------------------
// bf16 MFMA GEMM: H1b[M,512] = xb[M,512] @ B, with B given as Bbf[n][k] (n-major).
// 128x128 block tile, 4 waves (2x2), each wave 64x64 via 4x4 grid of 16x16x32.
__global__ __launch_bounds__(256) void mfma_gemm(const unsigned short* __restrict__ Abf,
                                                 const unsigned short* __restrict__ Bbf,
                                                 unsigned short* __restrict__ H1b, int M) {
    __shared__ short Asl[128*40];   // [m][k], pad to 40 (80 B rows, 16B aligned)
    __shared__ short Bsl[128*40];   // [n][k]
    int tid  = threadIdx.x;
    int wid  = tid >> 6, lane = tid & 63;
    int lrow = lane & 15, quad = lane >> 4;
    int wm = wid & 1, wn = wid >> 1;
    int row0 = blockIdx.y * 128, col0 = blockIdx.x * 128;

    floatx4 acc[4][4];
#pragma unroll
    for (int mm = 0; mm < 4; mm++)
#pragma unroll
        for (int nn = 0; nn < 4; nn++) acc[mm][nn] = (floatx4){0.f,0.f,0.f,0.f};

    for (int k0 = 0; k0 < 512; k0 += 32) {
#pragma unroll
        for (int it = 0; it < 2; ++it) {
            int q  = tid + it*256;           // 512 chunks of 16B per tile
            int r  = q >> 2, kk = (q & 3) * 8;
            int ar = row0 + r; ar = ar < M ? ar : M - 1;
            *(short8*)(&Asl[r*40 + kk]) =
                *(const short8*)(Abf + (size_t)ar*512 + k0 + kk);
            *(short8*)(&Bsl[r*40 + kk]) =
                *(const short8*)(Bbf + (size_t)(col0 + r)*512 + k0 + kk);
        }
        __syncthreads();
        short8 af[4], bfr[4];
#pragma unroll
        for (int mm = 0; mm < 4; ++mm)
            af[mm] = *(const short8*)(&Asl[(wm*64 + mm*16 + lrow)*40 + quad*8]);
#pragma unroll
        for (int nn = 0; nn < 4; ++nn)
            bfr[nn] = *(const short8*)(&Bsl[(wn*64 + nn*16 + lrow)*40 + quad*8]);
#pragma unroll
        for (int mm = 0; mm < 4; ++mm)
#pragma unroll
            for (int nn = 0; nn < 4; ++nn)
                acc[mm][nn] = __builtin_amdgcn_mfma_f32_16x16x32_bf16(
                    af[mm], bfr[nn], acc[mm][nn], 0, 0, 0);
        __syncthreads();
    }

#pragma unroll
    for (int mm = 0; mm < 4; ++mm) {
        int rbase = row0 + wm*64 + mm*16 + quad*4;
#pragma unroll
        for (int nn = 0; nn < 4; ++nn) {
            int c = col0 + wn*64 + nn*16 + lrow;
#pragma unroll
            for (int r = 0; r < 4; ++r) {
                int grow = rbase + r;
                if (grow < M)
                    H1b[(size_t)grow*512 + c] = f2bf(acc[mm][nn][r]);
            }
        }
    }
}

// ---------------------------------------------------------------------------
// Per-(node,head) attention dots from bf16 H1
__global__ void dots1(const unsigned short* __restrict__ H1b,
                      const float* __restrict__ a_heads,
                      float* __restrict__ srcdot, float* __restrict__ dstdot) {
    int t = blockIdx.x*256 + threadIdx.x;
    if (t >= N_NODES*NHEADS) return;
    int i = t >> 3, hd = t & 7;
    const unsigned short* hrow = H1b + (size_t)i*HD + hd*NHID;
    const float* as = a_heads + hd*2*NHID;
    const float* ad = as + NHID;
    float s0 = 0.f, s1 = 0.f;
#pragma unroll
    for (int d = 0; d < NHID; d += 8) {
        short8 hv = *(const short8*)(hrow + d);
#pragma unroll
        for (int j = 0; j < 8; j++) {
            float h = bf2f((unsigned short)hv[j]);
            s0 = fmaf(h, as[d+j], s0);
            s1 = fmaf(h, ad[d+j], s1);
        }
    }
    srcdot[t] = s0; dstdot[t] = s1;
}

// Per-edge weights (all heads)
__global__ void edge_w1(const int* __restrict__ row, const int* __restrict__ col,
                        const float* __restrict__ srcdot, const float* __restrict__ dstdot,
                        float* __restrict__ Wedge) {
    int e = blockIdx.x*256 + threadIdx.x;
    if (e >= N_EDGES) return;
    int r = row[e], c = col[e];
#pragma unroll
    for (int hd = 0; hd < NHEADS; hd++) {
        float s = srcdot[r*NHEADS+hd] + dstdot[c*NHEADS+hd];
        float lr = s > 0.f ? s : ALPHA*s;
        Wedge[(size_t)e*NHEADS + hd] = __expf(-lr);
    }
}

// ---------------------------------------------------------------------------
// CSR build
__global__ void zero_deg(int* __restrict__ deg) {
    int i = blockIdx.x*256 + threadIdx.x;
    if (i < N_NODES) deg[i] = 0;
}
__global__ void histk(const int* __restrict__ row, int* __restrict__ deg) {
    int e = blockIdx.x*256 + threadIdx.x;
    if (e < N_EDGES) atomicAdd(&deg[row[e]], 1);
}
__global__ void scanA(const int* __restrict__ deg, int* __restrict__ row_ptr,
                      int* __restrict__ chunk_tot) {
    __shared__ int s[256];
    int t = threadIdx.x;
    int idx = blockIdx.x*256 + t;
    int v = (idx < N_NODES) ? deg[idx] : 0;
    s[t] = v;
    __syncthreads();
#pragma unroll
    for (int off = 1; off < 256; off <<= 1) {
        int x = (t >= off) ? s[t-off] : 0;
        __syncthreads();
        s[t] += x;
        __syncthreads();
    }
    if (idx < N_NODES) row_ptr[idx] = s[t] - v;
    if (t == 255) chunk_tot[blockIdx.x] = s[t];
}
__global__ void scanB(const int* __restrict__ chunk_tot, int* __restrict__ chunk_off,
                      int* __restrict__ row_ptr) {
    __shared__ int s[256];
    int t = threadIdx.x;
    int v = (t < NCHUNK) ? chunk_tot[t] : 0;
    s[t] = v;
    __syncthreads();
#pragma unroll
    for (int off = 1; off < 256; off <<= 1) {
        int x = (t >= off) ? s[t-off] : 0;
        __syncthreads();
        s[t] += x;
        __syncthreads();
    }
    if (t < NCHUNK) chunk_off[t] = s[t] - v;
    if (t == 255) row_ptr[N_NODES] = s[t];
}
__global__ void scanC(const int* __restrict__ chunk_off, int* __restrict__ row_ptr,
                      int* __restrict__ cursor) {
    int idx = blockIdx.x*256 + threadIdx.x;
    if (idx < N_NODES) {
        int rp = row_ptr[idx] + chunk_off[idx >> 8];
        row_ptr[idx] = rp;
        cursor[idx] = rp;
    }
}
__global__ void fillk(const int* __restrict__ row, const int* __restrict__ col,
                      int* __restrict__ cursor, int* __restrict__ csr_eid,
                      int* __restrict__ csr_col) {
    int e = blockIdx.x*256 + threadIdx.x;
    if (e >= N_EDGES) return;
    int r = row[e];
    int pos = atomicAdd(&cursor[r], 1);
    csr_eid[pos] = e;
    csr_col[pos] = col[e];
}

// ---------------------------------------------------------------------------
// Layer-1 aggregation + ELU. Wave per (node, head); lane = feature; 4x unroll.
__global__ __launch_bounds__(256) void agg1(const unsigned short* __restrict__ H1b,
                                            const float* __restrict__ Wedge,
                                            const int* __restrict__ row_ptr,
                                            const int* __restrict__ csr_eid,
                                            const int* __restrict__ csr_col,
                                            unsigned short* __restrict__ hcatb) {
    int wave = (blockIdx.x*256 + threadIdx.x) >> 6;
    int lane = threadIdx.x & 63;
    if (wave >= N_NODES*NHEADS) return;
    int i = wave >> 3, hd = wave & 7;
    int start = row_ptr[i], end = row_ptr[i+1];
    int base = hd*NHID + lane;
    float acc = 0.f, den = 0.f;
    int k = start;
    for (; k + 4 <= end; k += 4) {
        int e0 = csr_eid[k],   e1 = csr_eid[k+1], e2 = csr_eid[k+2], e3 = csr_eid[k+3];
        int c0 = csr_col[k],   c1 = csr_col[k+1], c2 = csr_col[k+2], c3 = csr_col[k+3];
        float w0 = Wedge[(size_t)e0*NHEADS + hd];
        float w1 = Wedge[(size_t)e1*NHEADS + hd];
        float w2 = Wedge[(size_t)e2*NHEADS + hd];
        float w3 = Wedge[(size_t)e3*NHEADS + hd];
        float h0 = bf2f(H1b[(size_t)c0*HD + base]);
        float h1 = bf2f(H1b[(size_t)c1*HD + base]);
        float h2 = bf2f(H1b[(size_t)c2*HD + base]);
        float h3 = bf2f(H1b[(size_t)c3*HD + base]);
        den += (w0 + w1) + (w2 + w3);
        acc = fmaf(w0, h0, acc);
        acc = fmaf(w1, h1, acc);
        acc = fmaf(w2, h2, acc);
        acc = fmaf(w3, h3, acc);
    }
    for (; k < end; ++k) {
        int e = csr_eid[k];
        int c = csr_col[k];
        float w = Wedge[(size_t)e*NHEADS + hd];
        den += w;
        acc = fmaf(w, bf2f(H1b[(size_t)c*HD + base]), acc);
    }
    float o = acc / (den + EPS_F);
    o = o > 0.f ? o : (__expf(o) - 1.f);       // ELU
    hcatb[(size_t)i*HD + base] = f2bf(o);
}

// ---------------------------------------------------------------------------
// Layer 2: H2[N,40] = hcat[N,512] @ W_out[512,40]
__global__ void gemm2(const unsigned short* __restrict__ hcatb,
                      const float* __restrict__ Wout, float* __restrict__ H2) {
    int t = blockIdx.x*256 + threadIdx.x;
    if (t >= N_NODES*NCLASS) return;
    int i = t / NCLASS, c = t - i*NCLASS;
    const unsigned short* hr = hcatb + (size_t)i*HD;
    float acc = 0.f;
#pragma unroll 8
    for (int k = 0; k < HD; k++)
        acc = fmaf(bf2f(hr[k]), Wout[k*NCLASS + c], acc);
    H2[t] = acc;
}

__global__ void dots2(const float* __restrict__ H2, const float* __restrict__ a_out,
                      float* __restrict__ src2, float* __restrict__ dst2) {
    int i = blockIdx.x*256 + threadIdx.x;
    if (i >= N_NODES) return;
    float s0 = 0.f, s1 = 0.f;
#pragma unroll
    for (int c = 0; c < NCLASS; c++) {
        float h = H2[(size_t)i*NCLASS + c];
        s0 = fmaf(h, a_out[c], s0);
        s1 = fmaf(h, a_out[NCLASS + c], s1);
    }
    src2[i] = s0; dst2[i] = s1;
}

__global__ void edge_w2(const int* __restrict__ row, const int* __restrict__ col,
                        const float* __restrict__ src2, const float* __restrict__ dst2,
                        float* __restrict__ w2) {
    int e = blockIdx.x*256 + threadIdx.x;
    if (e >= N_EDGES) return;
    float s = src2[row[e]] + dst2[col[e]];
    float lr = s > 0.f ? s : ALPHA*s;
    w2[e] = __expf(-lr);
}

// Final aggregation (no ELU). Wave per node; lanes 0..39 = class; 4x unroll.
__global__ __launch_bounds__(256) void agg2(const float* __restrict__ H2,
                                            const float* __restrict__ w2,
                                            const int* __restrict__ row_ptr,
                                            const int* __restrict__ csr_eid,
                                            const int* __restrict__ csr_col,
                                            float* __restrict__ out) {
    int wave = (blockIdx.x*256 + threadIdx.x) >> 6;
    int lane = threadIdx.x & 63;
    if (wave >= N_NODES) return;
    int start = row_ptr[wave], end = row_ptr[wave+1];
    int l = lane < NCLASS ? lane : 0;
    float acc = 0.f, den = 0.f;
    int k = start;
    for (; k + 4 <= end; k += 4) {
        int e0 = csr_eid[k],   e1 = csr_eid[k+1], e2 = csr_eid[k+2], e3 = csr_eid[k+3];
        int c0 = csr_col[k],   c1 = csr_col[k+1], c2 = csr_col[k+2], c3 = csr_col[k+3];
        float w0 = w2[e0], w1 = w2[e1], w2v = w2[e2], w3 = w2[e3];
        float h0 = H2[(size_t)c0*NCLASS + l];
        float h1 = H2[(size_t)c1*NCLASS + l];
        float h2 = H2[(size_t)c2*NCLASS + l];
        float h3 = H2[(size_t)c3*NCLASS + l];
        den += (w0 + w1) + (w2v + w3);
        acc = fmaf(w0, h0, acc);
        acc = fmaf(w1, h1, acc);
        acc = fmaf(w2v, h2, acc);
        acc = fmaf(w3, h3, acc);
    }
    for (; k < end; ++k) {
        int e = csr_eid[k];
        int c = csr_col[k];
        float w = w2[e];
        den += w;
        acc = fmaf(w, H2[(size_t)c*NCLASS + l], acc);
    }
    if (lane < NCLASS)
        out[(size_t)wave*NCLASS + lane] = acc / (den + EPS_F);
}

// ---------------------------------------------------------------------------
extern "C" void kernel_launch(void* const* d_in, const int* in_sizes, int n_in,
                              void* d_out, int out_size, void* d_ws, size_t ws_size,
                              hipStream_t stream) {
    const float* x       = (const float*)d_in[0];
    const float* W_heads = (const float*)d_in[1];
    const float* a_heads = (const float*)d_in[2];
    const float* W_out   = (const float*)d_in[3];
    const float* a_out   = (const float*)d_in[4];
    const int*   ei      = (const int*)d_in[5];
    const int*   row     = ei;
    const int*   col     = ei + N_EDGES;
    float* out = (float*)d_out;

    char* ws = (char*)d_ws;
    size_t off = 0;
    auto alloc = [&](size_t bytes) {
        char* p = ws + off;
        off = (off + bytes + 255) & ~(size_t)255;
        return p;
    };
    unsigned short* Wrb   = (unsigned short*)alloc((size_t)512*512*2);
    unsigned short* xb    = (unsigned short*)alloc((size_t)N_NODES*512*2);
    unsigned short* H1b   = (unsigned short*)alloc((size_t)N_NODES*HD*2);
    unsigned short* hcatb = (unsigned short*)alloc((size_t)N_NODES*HD*2);
    float* srcdot  = (float*)alloc((size_t)N_NODES*NHEADS*4);
    float* dstdot  = (float*)alloc((size_t)N_NODES*NHEADS*4);
    float* Wedge   = (float*)alloc((size_t)N_EDGES*NHEADS*4);
    int*   deg     = (int*)alloc((size_t)N_NODES*4);
    int*   row_ptr = (int*)alloc((size_t)(N_NODES+1)*4);
    int*   cursor  = (int*)alloc((size_t)N_NODES*4);
    int*   ctot    = (int*)alloc(256*4);
    int*   coff    = (int*)alloc(256*4);
    int*   csr_eid = (int*)alloc((size_t)N_EDGES*4);
    int*   csr_col = (int*)alloc((size_t)N_EDGES*4);
    float* H2      = (float*)alloc((size_t)N_NODES*NCLASS*4);
    float* src2    = (float*)alloc((size_t)N_NODES*4);
    float* dst2    = (float*)alloc((size_t)N_NODES*4);
    float* w2      = (float*)alloc((size_t)N_EDGES*4);
    (void)ws_size;

    const int EB = (N_EDGES + 255)/256;
    const int NB = (N_NODES + 255)/256;

    // Layer 1
    castX<<<(N_NODES*512/4 + 255)/256, 256, 0, stream>>>(x, xb);
    repackWb<<<(512*512 + 255)/256, 256, 0, stream>>>(W_heads, Wrb);
    {
        dim3 grid(4, (N_NODES + 127)/128);
        mfma_gemm<<<grid, 256, 0, stream>>>(xb, Wrb, H1b, N_NODES);
    }
    dots1<<<(N_NODES*NHEADS + 255)/256, 256, 0, stream>>>(H1b, a_heads, srcdot, dstdot);
    edge_w1<<<EB, 256, 0, stream>>>(row, col, srcdot, dstdot, Wedge);

    // CSR
    zero_deg<<<NB, 256, 0, stream>>>(deg);
    histk<<<EB, 256, 0, stream>>>(row, deg);
    scanA<<<NCHUNK, 256, 0, stream>>>(deg, row_ptr, ctot);
    scanB<<<1, 256, 0, stream>>>(ctot, coff, row_ptr);
    scanC<<<NCHUNK, 256, 0, stream>>>(coff, row_ptr, cursor);
    fillk<<<EB, 256, 0, stream>>>(row, col, cursor, csr_eid, csr_col);

    agg1<<<(N_NODES*NHEADS*64 + 255)/256, 256, 0, stream>>>(H1b, Wedge, row_ptr,
                                                            csr_eid, csr_col, hcatb);

    // Layer 2
    gemm2<<<(N_NODES*NCLASS + 255)/256, 256, 0, stream>>>(hcatb, W_out, H2);
    dots2<<<NB, 256, 0, stream>>>(H2, a_out, src2, dst2);
    edge_w2<<<EB, 256, 0, stream>>>(row, col, src2, dst2, w2);
    agg2<<<(N_NODES*64 + 255)/256, 256, 0, stream>>>(H2, w2, row_ptr,
                                                     csr_eid, csr_col, out);
}

// Round 4
// 567.986 us; speedup vs baseline: 2.6827x; 1.5081x over previous
//
#include <hip/hip_runtime.h>
#include <hip/hip_bf16.h>

#define N_NODES 50000
#define N_EDGES 800000
#define NFEAT   512
#define NHID    64
#define NHEADS  8
#define NCLASS  40
#define HD      (NHEADS*NHID)   // 512
#define ALPHA   0.2f
#define EPS_F   1e-16f
#define NCHUNK  ((N_NODES + 255)/256)   // 196

typedef __attribute__((ext_vector_type(8))) short short8;
typedef __attribute__((ext_vector_type(4))) float floatx4;

__device__ __forceinline__ float bf2f(unsigned short u) {
    union { unsigned int i; float f; } v; v.i = ((unsigned int)u) << 16; return v.f;
}
__device__ __forceinline__ unsigned short f2bf(float f) {
    union { __hip_bfloat16 h; unsigned short u; } cv;
    cv.h = __float2bfloat16(f);
    return cv.u;
}

// ---------------------------------------------------------------------------
// Cast x [N,512] fp32 -> bf16 bits
__global__ void castX(const float* __restrict__ x, unsigned short* __restrict__ xb) {
    int idx = blockIdx.x*256 + threadIdx.x;      // one per 4 elements
    if (idx >= N_NODES*512/4) return;
    float4 v = ((const float4*)x)[idx];
    ushort4 o;
    o.x = f2bf(v.x); o.y = f2bf(v.y); o.z = f2bf(v.z); o.w = f2bf(v.w);
    ((ushort4*)xb)[idx] = o;
}

// Repack W_heads [H][512][64] -> Wrb[n][k] bf16 (B^T layout: n=hd*64+d, k=feat)
__global__ void repackWb(const float* __restrict__ Wh, unsigned short* __restrict__ Wrb) {
    int idx = blockIdx.x*256 + threadIdx.x;      // n*512 + k
    if (idx >= 512*512) return;
    int n = idx >> 9, k = idx & 511;
    int hd = n >> 6, d = n & 63;
    Wrb[idx] = f2bf(Wh[(size_t)hd*NFEAT*NHID + (size_t)k*NHID + d]);
}

// Repack W_out [512][40] -> Woutb[n][k] bf16 (n padded to 64, zeros beyond 40)
__global__ void repackWout(const float* __restrict__ Wo, unsigned short* __restrict__ Wob) {
    int idx = blockIdx.x*256 + threadIdx.x;      // n*512 + k, n < 64
    if (idx >= 64*512) return;
    int n = idx >> 9, k = idx & 511;
    float v = (n < NCLASS) ? Wo[(size_t)k*NCLASS + n] : 0.f;
    Wob[idx] = f2bf(v);
}

// ---------------------------------------------------------------------------
// bf16 MFMA GEMM: H1b[M,512] = xb[M,512] @ B, with B given as Bbf[n][k] (n-major).
// 128x128 block tile, 4 waves (2x2), each wave 64x64 via 4x4 grid of 16x16x32.
__global__ __launch_bounds__(256) void mfma_gemm(const unsigned short* __restrict__ Abf,
                                                 const unsigned short* __restrict__ Bbf,
                                                 unsigned short* __restrict__ H1b, int M) {
    __shared__ short Asl[128*40];   // [m][k], pad to 40
    __shared__ short Bsl[128*40];   // [n][k]
    int tid  = threadIdx.x;
    int wid  = tid >> 6, lane = tid & 63;
    int lrow = lane & 15, quad = lane >> 4;
    int wm = wid & 1, wn = wid >> 1;
    int row0 = blockIdx.y * 128, col0 = blockIdx.x * 128;

    floatx4 acc[4][4];
#pragma unroll
    for (int mm = 0; mm < 4; mm++)
#pragma unroll
        for (int nn = 0; nn < 4; nn++) acc[mm][nn] = (floatx4){0.f,0.f,0.f,0.f};

    for (int k0 = 0; k0 < 512; k0 += 32) {
#pragma unroll
        for (int it = 0; it < 2; ++it) {
            int q  = tid + it*256;           // 512 chunks of 16B per tile
            int r  = q >> 2, kk = (q & 3) * 8;
            int ar = row0 + r; ar = ar < M ? ar : M - 1;
            *(short8*)(&Asl[r*40 + kk]) =
                *(const short8*)(Abf + (size_t)ar*512 + k0 + kk);
            *(short8*)(&Bsl[r*40 + kk]) =
                *(const short8*)(Bbf + (size_t)(col0 + r)*512 + k0 + kk);
        }
        __syncthreads();
        short8 af[4], bfr[4];
#pragma unroll
        for (int mm = 0; mm < 4; ++mm)
            af[mm] = *(const short8*)(&Asl[(wm*64 + mm*16 + lrow)*40 + quad*8]);
#pragma unroll
        for (int nn = 0; nn < 4; ++nn)
            bfr[nn] = *(const short8*)(&Bsl[(wn*64 + nn*16 + lrow)*40 + quad*8]);
#pragma unroll
        for (int mm = 0; mm < 4; ++mm)
#pragma unroll
            for (int nn = 0; nn < 4; ++nn)
                acc[mm][nn] = __builtin_amdgcn_mfma_f32_16x16x32_bf16(
                    af[mm], bfr[nn], acc[mm][nn], 0, 0, 0);
        __syncthreads();
    }

#pragma unroll
    for (int mm = 0; mm < 4; ++mm) {
        int rbase = row0 + wm*64 + mm*16 + quad*4;
#pragma unroll
        for (int nn = 0; nn < 4; ++nn) {
            int c = col0 + wn*64 + nn*16 + lrow;
#pragma unroll
            for (int r = 0; r < 4; ++r) {
                int grow = rbase + r;
                if (grow < M)
                    H1b[(size_t)grow*512 + c] = f2bf(acc[mm][nn][r]);
            }
        }
    }
}

// ---------------------------------------------------------------------------
// Layer-2 MFMA GEMM: H2[M,40] = hcatb[M,512] @ Woutb^T; tile 256x64, 4 waves in m.
__global__ __launch_bounds__(256) void mfma_gemm2(const unsigned short* __restrict__ Abf,
                                                  const unsigned short* __restrict__ Bbf,
                                                  float* __restrict__ H2, int M) {
    __shared__ short Asl[256*40];
    __shared__ short Bsl[64*40];
    int tid  = threadIdx.x;
    int wid  = tid >> 6, lane = tid & 63;
    int lrow = lane & 15, quad = lane >> 4;
    int row0 = blockIdx.x * 256;

    floatx4 acc[4][4];
#pragma unroll
    for (int mm = 0; mm < 4; mm++)
#pragma unroll
        for (int nn = 0; nn < 4; nn++) acc[mm][nn] = (floatx4){0.f,0.f,0.f,0.f};

    for (int k0 = 0; k0 < 512; k0 += 32) {
#pragma unroll
        for (int it = 0; it < 4; ++it) {     // A: 256 rows x 32k = 1024 chunks
            int q  = tid + it*256;
            int r  = q >> 2, kk = (q & 3) * 8;
            int ar = row0 + r; ar = ar < M ? ar : M - 1;
            *(short8*)(&Asl[r*40 + kk]) =
                *(const short8*)(Abf + (size_t)ar*512 + k0 + kk);
        }
        {                                    // B: 64 rows x 32k = 256 chunks (ALL threads)
            int r = tid >> 2, kk = (tid & 3) * 8;
            *(short8*)(&Bsl[r*40 + kk]) =
                *(const short8*)(Bbf + (size_t)r*512 + k0 + kk);
        }
        __syncthreads();
        short8 af[4], bfr[4];
#pragma unroll
        for (int mm = 0; mm < 4; ++mm)
            af[mm] = *(const short8*)(&Asl[(wid*64 + mm*16 + lrow)*40 + quad*8]);
#pragma unroll
        for (int nn = 0; nn < 4; ++nn)
            bfr[nn] = *(const short8*)(&Bsl[(nn*16 + lrow)*40 + quad*8]);
#pragma unroll
        for (int mm = 0; mm < 4; ++mm)
#pragma unroll
            for (int nn = 0; nn < 4; ++nn)
                acc[mm][nn] = __builtin_amdgcn_mfma_f32_16x16x32_bf16(
                    af[mm], bfr[nn], acc[mm][nn], 0, 0, 0);
        __syncthreads();
    }

#pragma unroll
    for (int mm = 0; mm < 4; ++mm) {
        int rbase = row0 + wid*64 + mm*16 + quad*4;
#pragma unroll
        for (int nn = 0; nn < 4; ++nn) {
            int c = nn*16 + lrow;
            if (c < NCLASS) {
#pragma unroll
                for (int r = 0; r < 4; ++r) {
                    int grow = rbase + r;
                    if (grow < M)
                        H2[(size_t)grow*NCLASS + c] = acc[mm][nn][r];
                }
            }
        }
    }
}

// ---------------------------------------------------------------------------
// Per-(node,head) attention dots from bf16 H1
__global__ void dots1(const unsigned short* __restrict__ H1b,
                      const float* __restrict__ a_heads,
                      float* __restrict__ srcdot, float* __restrict__ dstdot) {
    int t = blockIdx.x*256 + threadIdx.x;
    if (t >= N_NODES*NHEADS) return;
    int i = t >> 3, hd = t & 7;
    const unsigned short* hrow = H1b + (size_t)i*HD + hd*NHID;
    const float* as = a_heads + hd*2*NHID;
    const float* ad = as + NHID;
    float s0 = 0.f, s1 = 0.f;
#pragma unroll
    for (int d = 0; d < NHID; d += 8) {
        short8 hv = *(const short8*)(hrow + d);
#pragma unroll
        for (int j = 0; j < 8; j++) {
            float h = bf2f((unsigned short)hv[j]);
            s0 = fmaf(h, as[d+j], s0);
            s1 = fmaf(h, ad[d+j], s1);
        }
    }
    srcdot[t] = s0; dstdot[t] = s1;
}

// Per-edge weights (all heads), vectorized
__global__ void edge_w1(const int* __restrict__ row, const int* __restrict__ col,
                        const float* __restrict__ srcdot, const float* __restrict__ dstdot,
                        float* __restrict__ Wedge) {
    int e = blockIdx.x*256 + threadIdx.x;
    if (e >= N_EDGES) return;
    int r = row[e], c = col[e];
    float4 sa = *(const float4*)(srcdot + (size_t)r*8);
    float4 sb = *(const float4*)(srcdot + (size_t)r*8 + 4);
    float4 da = *(const float4*)(dstdot + (size_t)c*8);
    float4 db = *(const float4*)(dstdot + (size_t)c*8 + 4);
    float s[8] = {sa.x+da.x, sa.y+da.y, sa.z+da.z, sa.w+da.w,
                  sb.x+db.x, sb.y+db.y, sb.z+db.z, sb.w+db.w};
    float o[8];
#pragma unroll
    for (int j = 0; j < 8; j++) {
        float lr = s[j] > 0.f ? s[j] : ALPHA*s[j];
        o[j] = __expf(-lr);
    }
    *(float4*)(Wedge + (size_t)e*8)     = make_float4(o[0], o[1], o[2], o[3]);
    *(float4*)(Wedge + (size_t)e*8 + 4) = make_float4(o[4], o[5], o[6], o[7]);
}

// ---------------------------------------------------------------------------
// CSR build
__global__ void zero_deg(int* __restrict__ deg) {
    int i = blockIdx.x*256 + threadIdx.x;
    if (i < N_NODES) deg[i] = 0;
}
__global__ void histk(const int* __restrict__ row, int* __restrict__ deg) {
    int e = blockIdx.x*256 + threadIdx.x;
    if (e < N_EDGES) atomicAdd(&deg[row[e]], 1);
}
__global__ void scanA(const int* __restrict__ deg, int* __restrict__ row_ptr,
                      int* __restrict__ chunk_tot) {
    __shared__ int s[256];
    int t = threadIdx.x;
    int idx = blockIdx.x*256 + t;
    int v = (idx < N_NODES) ? deg[idx] : 0;
    s[t] = v;
    __syncthreads();
#pragma unroll
    for (int off = 1; off < 256; off <<= 1) {
        int x = (t >= off) ? s[t-off] : 0;
        __syncthreads();
        s[t] += x;
        __syncthreads();
    }
    if (idx < N_NODES) row_ptr[idx] = s[t] - v;
    if (t == 255) chunk_tot[blockIdx.x] = s[t];
}
__global__ void scanB(const int* __restrict__ chunk_tot, int* __restrict__ chunk_off,
                      int* __restrict__ row_ptr) {
    __shared__ int s[256];
    int t = threadIdx.x;
    int v = (t < NCHUNK) ? chunk_tot[t] : 0;
    s[t] = v;
    __syncthreads();
#pragma unroll
    for (int off = 1; off < 256; off <<= 1) {
        int x = (t >= off) ? s[t-off] : 0;
        __syncthreads();
        s[t] += x;
        __syncthreads();
    }
    if (t < NCHUNK) chunk_off[t] = s[t] - v;
    if (t == 255) row_ptr[N_NODES] = s[t];
}
__global__ void scanC(const int* __restrict__ chunk_off, int* __restrict__ row_ptr,
                      int* __restrict__ cursor) {
    int idx = blockIdx.x*256 + threadIdx.x;
    if (idx < N_NODES) {
        int rp = row_ptr[idx] + chunk_off[idx >> 8];
        row_ptr[idx] = rp;
        cursor[idx] = rp;
    }
}
__global__ void fillk(const int* __restrict__ row, const int* __restrict__ col,
                      int* __restrict__ cursor, int* __restrict__ csr_eid,
                      int* __restrict__ csr_col) {
    int e = blockIdx.x*256 + threadIdx.x;
    if (e >= N_EDGES) return;
    int r = row[e];
    int pos = atomicAdd(&cursor[r], 1);
    csr_eid[pos] = e;
    csr_col[pos] = col[e];
}

// ---------------------------------------------------------------------------
// Layer-1 aggregation + ELU. ONE WAVE PER NODE, all 8 heads in registers.
__global__ __launch_bounds__(256) void agg1(const unsigned short* __restrict__ H1b,
                                            const float* __restrict__ Wedge,
                                            const int* __restrict__ row_ptr,
                                            const int* __restrict__ csr_eid,
                                            const int* __restrict__ csr_col,
                                            unsigned short* __restrict__ hcatb) {
    int wave = (blockIdx.x*256 + threadIdx.x) >> 6;
    int lane = threadIdx.x & 63;
    if (wave >= N_NODES) return;
    int start = row_ptr[wave], end = row_ptr[wave+1];
    float acc[8], den[8];
#pragma unroll
    for (int j = 0; j < 8; j++) { acc[j] = 0.f; den[j] = 0.f; }

    int k = start;
    for (; k + 2 <= end; k += 2) {
        int e0 = csr_eid[k], e1 = csr_eid[k+1];
        int c0 = csr_col[k], c1 = csr_col[k+1];
        float4 wa0 = *(const float4*)(Wedge + (size_t)e0*8);
        float4 wb0 = *(const float4*)(Wedge + (size_t)e0*8 + 4);
        float4 wa1 = *(const float4*)(Wedge + (size_t)e1*8);
        float4 wb1 = *(const float4*)(Wedge + (size_t)e1*8 + 4);
        const unsigned short* r0 = H1b + (size_t)c0*HD + lane;
        const unsigned short* r1 = H1b + (size_t)c1*HD + lane;
        float h0[8], h1[8];
#pragma unroll
        for (int j = 0; j < 8; j++) { h0[j] = bf2f(r0[j*64]); h1[j] = bf2f(r1[j*64]); }
        float w0[8] = {wa0.x, wa0.y, wa0.z, wa0.w, wb0.x, wb0.y, wb0.z, wb0.w};
        float w1[8] = {wa1.x, wa1.y, wa1.z, wa1.w, wb1.x, wb1.y, wb1.z, wb1.w};
#pragma unroll
        for (int j = 0; j < 8; j++) {
            den[j] += w0[j] + w1[j];
            acc[j] = fmaf(w0[j], h0[j], acc[j]);
            acc[j] = fmaf(w1[j], h1[j], acc[j]);
        }
    }
    for (; k < end; ++k) {
        int e = csr_eid[k];
        int c = csr_col[k];
        float4 wa = *(const float4*)(Wedge + (size_t)e*8);
        float4 wb = *(const float4*)(Wedge + (size_t)e*8 + 4);
        const unsigned short* r0 = H1b + (size_t)c*HD + lane;
        float w[8] = {wa.x, wa.y, wa.z, wa.w, wb.x, wb.y, wb.z, wb.w};
#pragma unroll
        for (int j = 0; j < 8; j++) {
            float h = bf2f(r0[j*64]);
            den[j] += w[j];
            acc[j] = fmaf(w[j], h, acc[j]);
        }
    }
#pragma unroll
    for (int j = 0; j < 8; j++) {
        float o = acc[j] / (den[j] + EPS_F);
        o = o > 0.f ? o : (__expf(o) - 1.f);   // ELU
        hcatb[(size_t)wave*HD + j*64 + lane] = f2bf(o);
    }
}

// ---------------------------------------------------------------------------
__global__ void dots2(const float* __restrict__ H2, const float* __restrict__ a_out,
                      float* __restrict__ src2, float* __restrict__ dst2) {
    int i = blockIdx.x*256 + threadIdx.x;
    if (i >= N_NODES) return;
    float s0 = 0.f, s1 = 0.f;
#pragma unroll
    for (int c = 0; c < NCLASS; c++) {
        float h = H2[(size_t)i*NCLASS + c];
        s0 = fmaf(h, a_out[c], s0);
        s1 = fmaf(h, a_out[NCLASS + c], s1);
    }
    src2[i] = s0; dst2[i] = s1;
}

__global__ void edge_w2(const int* __restrict__ row, const int* __restrict__ col,
                        const float* __restrict__ src2, const float* __restrict__ dst2,
                        float* __restrict__ w2) {
    int e = blockIdx.x*256 + threadIdx.x;
    if (e >= N_EDGES) return;
    float s = src2[row[e]] + dst2[col[e]];
    float lr = s > 0.f ? s : ALPHA*s;
    w2[e] = __expf(-lr);
}

// Final aggregation (no ELU). Wave per node; lanes 0..39 = class; 4x unroll.
__global__ __launch_bounds__(256) void agg2(const float* __restrict__ H2,
                                            const float* __restrict__ w2,
                                            const int* __restrict__ row_ptr,
                                            const int* __restrict__ csr_eid,
                                            const int* __restrict__ csr_col,
                                            float* __restrict__ out) {
    int wave = (blockIdx.x*256 + threadIdx.x) >> 6;
    int lane = threadIdx.x & 63;
    if (wave >= N_NODES) return;
    int start = row_ptr[wave], end = row_ptr[wave+1];
    int l = lane < NCLASS ? lane : 0;
    float acc = 0.f, den = 0.f;
    int k = start;
    for (; k + 4 <= end; k += 4) {
        int e0 = csr_eid[k],   e1 = csr_eid[k+1], e2 = csr_eid[k+2], e3 = csr_eid[k+3];
        int c0 = csr_col[k],   c1 = csr_col[k+1], c2 = csr_col[k+2], c3 = csr_col[k+3];
        float w0 = w2[e0], w1 = w2[e1], w2v = w2[e2], w3 = w2[e3];
        float h0 = H2[(size_t)c0*NCLASS + l];
        float h1 = H2[(size_t)c1*NCLASS + l];
        float h2 = H2[(size_t)c2*NCLASS + l];
        float h3 = H2[(size_t)c3*NCLASS + l];
        den += (w0 + w1) + (w2v + w3);
        acc = fmaf(w0, h0, acc);
        acc = fmaf(w1, h1, acc);
        acc = fmaf(w2v, h2, acc);
        acc = fmaf(w3, h3, acc);
    }
    for (; k < end; ++k) {
        int e = csr_eid[k];
        int c = csr_col[k];
        float w = w2[e];
        den += w;
        acc = fmaf(w, H2[(size_t)c*NCLASS + l], acc);
    }
    if (lane < NCLASS)
        out[(size_t)wave*NCLASS + lane] = acc / (den + EPS_F);
}

// ---------------------------------------------------------------------------
extern "C" void kernel_launch(void* const* d_in, const int* in_sizes, int n_in,
                              void* d_out, int out_size, void* d_ws, size_t ws_size,
                              hipStream_t stream) {
    const float* x       = (const float*)d_in[0];
    const float* W_heads = (const float*)d_in[1];
    const float* a_heads = (const float*)d_in[2];
    const float* W_out   = (const float*)d_in[3];
    const float* a_out   = (const float*)d_in[4];
    const int*   ei      = (const int*)d_in[5];
    const int*   row     = ei;
    const int*   col     = ei + N_EDGES;
    float* out = (float*)d_out;

    char* ws = (char*)d_ws;
    size_t off = 0;
    auto alloc = [&](size_t bytes) {
        char* p = ws + off;
        off = (off + bytes + 255) & ~(size_t)255;
        return p;
    };
    unsigned short* Wrb   = (unsigned short*)alloc((size_t)512*512*2);
    unsigned short* Wob   = (unsigned short*)alloc((size_t)64*512*2);
    unsigned short* xb    = (unsigned short*)alloc((size_t)N_NODES*512*2);
    unsigned short* H1b   = (unsigned short*)alloc((size_t)N_NODES*HD*2);
    unsigned short* hcatb = (unsigned short*)alloc((size_t)N_NODES*HD*2);
    float* srcdot  = (float*)alloc((size_t)N_NODES*NHEADS*4);
    float* dstdot  = (float*)alloc((size_t)N_NODES*NHEADS*4);
    float* Wedge   = (float*)alloc((size_t)N_EDGES*NHEADS*4);
    int*   deg     = (int*)alloc((size_t)N_NODES*4);
    int*   row_ptr = (int*)alloc((size_t)(N_NODES+1)*4);
    int*   cursor  = (int*)alloc((size_t)N_NODES*4);
    int*   ctot    = (int*)alloc(256*4);
    int*   coff    = (int*)alloc(256*4);
    int*   csr_eid = (int*)alloc((size_t)N_EDGES*4);
    int*   csr_col = (int*)alloc((size_t)N_EDGES*4);
    float* H2      = (float*)alloc((size_t)N_NODES*NCLASS*4);
    float* src2    = (float*)alloc((size_t)N_NODES*4);
    float* dst2    = (float*)alloc((size_t)N_NODES*4);
    float* w2      = (float*)alloc((size_t)N_EDGES*4);
    (void)ws_size;

    const int EB = (N_EDGES + 255)/256;
    const int NB = (N_NODES + 255)/256;

    // Layer 1
    castX<<<(N_NODES*512/4 + 255)/256, 256, 0, stream>>>(x, xb);
    repackWb<<<(512*512 + 255)/256, 256, 0, stream>>>(W_heads, Wrb);
    repackWout<<<(64*512 + 255)/256, 256, 0, stream>>>(W_out, Wob);
    {
        dim3 grid(4, (N_NODES + 127)/128);
        mfma_gemm<<<grid, 256, 0, stream>>>(xb, Wrb, H1b, N_NODES);
    }
    dots1<<<(N_NODES*NHEADS + 255)/256, 256, 0, stream>>>(H1b, a_heads, srcdot, dstdot);
    edge_w1<<<EB, 256, 0, stream>>>(row, col, srcdot, dstdot, Wedge);

    // CSR
    zero_deg<<<NB, 256, 0, stream>>>(deg);
    histk<<<EB, 256, 0, stream>>>(row, deg);
    scanA<<<NCHUNK, 256, 0, stream>>>(deg, row_ptr, ctot);
    scanB<<<1, 256, 0, stream>>>(ctot, coff, row_ptr);
    scanC<<<NCHUNK, 256, 0, stream>>>(coff, row_ptr, cursor);
    fillk<<<EB, 256, 0, stream>>>(row, col, cursor, csr_eid, csr_col);

    agg1<<<(N_NODES*64 + 255)/256, 256, 0, stream>>>(H1b, Wedge, row_ptr,
                                                     csr_eid, csr_col, hcatb);

    // Layer 2
    mfma_gemm2<<<(N_NODES + 255)/256, 256, 0, stream>>>(hcatb, Wob, H2, N_NODES);
    dots2<<<NB, 256, 0, stream>>>(H2, a_out, src2, dst2);
    edge_w2<<<EB, 256, 0, stream>>>(row, col, src2, dst2, w2);
    agg2<<<(N_NODES*64 + 255)/256, 256, 0, stream>>>(H2, w2, row_ptr,
                                                     csr_eid, csr_col, out);
}